// Round 1
// 239.628 us; speedup vs baseline: 1.0020x; 1.0020x over previous
//
#include <hip/hip_runtime.h>

// DynamicUpsamplingFilter: out[b,c,h,w] = sum_{dy,dx} f[b,3*dy+dx,h,w] * x[b,c,h+dy-1,w+dx-1]
// x: [4,128,180,320] f32, filters: [4,9,180,320] f32, out: [4,128,180,320] f32.
//
// R4: register-budget fix. R3's design needs ~140 VGPRs (18 filter float4s +
// 12 x float4s live) but compiled at 64 VGPRs (compiler's 8-wave default) ->
// filter cache spilled to scratch, row loads serialized, latency-bound at
// 33% HBM BW. Changes:
//   1. __launch_bounds__(256, 4): 128-VGPR cap (16 waves/CU; measured
//      occupancy was only ~12 waves/CU anyway).
//   2. Halo columns loaded as predicated scalar floats (only A.w / C.x were
//      used) -> per-row x footprint 12 -> 6 VGPRs, live set ~116 < 128.
//      Also halves L1 bytes for x and drops the edge cndmask fixups.

#define CC 128
#define HH 180
#define W4 80
#define WW (W4 * 4)    // 320
#define NF 9
#define CPT 8
#define H2 (HH / 2)    // 90
#define NCG (CC / CPT) // 16

__device__ __forceinline__ void fma_row(float4& acc, const float4 f0, const float4 f1,
                                        const float4 f2, const float aL, const float4 B,
                                        const float cR) {
    acc.x = fmaf(f0.x, aL,  fmaf(f1.x, B.x, fmaf(f2.x, B.y, acc.x)));
    acc.y = fmaf(f0.y, B.x, fmaf(f1.y, B.y, fmaf(f2.y, B.z, acc.y)));
    acc.z = fmaf(f0.z, B.y, fmaf(f1.z, B.z, fmaf(f2.z, B.w, acc.z)));
    acc.w = fmaf(f0.w, B.z, fmaf(f1.w, B.w, fmaf(f2.w, cR,  acc.w)));
}

__global__ __launch_bounds__(256, 4) void duf_kernel(
    const float* __restrict__ x,
    const float* __restrict__ f,
    float* __restrict__ out)
{
    int n = blockIdx.x * 256 + threadIdx.x;
    // n = ((b*H2 + h2)*NCG + cg)*W4 + w4  -> lanes consecutive in w4.
    // NCG*W4 = 1280 = 5 blocks -> h2 (and thus the row-clamp branch) is
    // block-uniform.
    int w4 = n % W4;
    int t  = n / W4;
    int cg = t % NCG;
    t /= NCG;
    int h2 = t % H2;
    int b  = t / H2;
    int h  = h2 * 2;

    const float4* f4 = (const float4*)f;
    float4* o4 = (float4*)out;

    // ---- register-cache the 9 taps for both output rows (18 float4 = 72 VGPR)
    float4 fr0[NF], fr1[NF];
    size_t fbase = ((size_t)(b * NF) * HH + h) * W4 + w4;
#pragma unroll
    for (int i = 0; i < NF; ++i) {
        fr0[i] = f4[fbase + (size_t)i * HH * W4];
        fr1[i] = f4[fbase + (size_t)i * HH * W4 + W4];
    }

    const bool at_l = (w4 == 0);
    const bool at_r = (w4 == W4 - 1);

    const int c0 = cg * CPT;
    for (int cc = 0; cc < CPT; ++cc) {
        const float* xc = x + (size_t)(b * CC + c0 + cc) * HH * WW;
        float4 a0 = make_float4(0.f, 0.f, 0.f, 0.f);
        float4 a1 = make_float4(0.f, 0.f, 0.f, 0.f);
#pragma unroll
        for (int r = 0; r < 4; ++r) {              // x rows h-1 .. h+2
            int hr = h - 1 + r;
            float4 B = make_float4(0.f, 0.f, 0.f, 0.f);
            float aL = 0.f, cR = 0.f;
            if (hr >= 0 && hr < HH) {              // block-uniform branch
                const float* xr = xc + (size_t)hr * WW;
                B = *(const float4*)(xr + w4 * 4);
                if (!at_l) aL = xr[w4 * 4 - 1];    // exec-masked scalar load
                if (!at_r) cR = xr[w4 * 4 + 4];    // exec-masked scalar load
            }
            if (r < 3) fma_row(a0, fr0[3*r  ], fr0[3*r+1], fr0[3*r+2], aL, B, cR);
            if (r > 0) fma_row(a1, fr1[3*r-3], fr1[3*r-2], fr1[3*r-1], aL, B, cR);
        }
        size_t ob = ((size_t)(b * CC + c0 + cc) * HH + h) * W4 + w4;
        o4[ob]      = a0;
        o4[ob + W4] = a1;
    }
}

extern "C" void kernel_launch(void* const* d_in, const int* in_sizes, int n_in,
                              void* d_out, int out_size, void* d_ws, size_t ws_size,
                              hipStream_t stream) {
    const float* x = (const float*)d_in[0];
    const float* f = (const float*)d_in[1];
    float* out = (float*)d_out;

    int B = in_sizes[0] / (CC * HH * W4 * 4 * 4); // bytes -> batch (4)
    (void)B;
    int total = 4 * H2 * NCG * W4;                // 460800 threads
    duf_kernel<<<total / 256, 256, 0, stream>>>(x, f, out);
}